// Round 1
// baseline (175.957 us; speedup 1.0000x reference)
//
#include <hip/hip_runtime.h>

// ---------- small vector helpers ----------
struct V3 { float x, y, z; };

__device__ __forceinline__ V3 v3add(V3 a, V3 b){ return {a.x+b.x, a.y+b.y, a.z+b.z}; }
__device__ __forceinline__ V3 v3sub(V3 a, V3 b){ return {a.x-b.x, a.y-b.y, a.z-b.z}; }
__device__ __forceinline__ V3 v3scale(V3 a, float s){ return {a.x*s, a.y*s, a.z*s}; }
__device__ __forceinline__ V3 v3mul(V3 a, V3 b){ return {a.x*b.x, a.y*b.y, a.z*b.z}; }
__device__ __forceinline__ float dot3(V3 a, V3 b){ return fmaf(a.x,b.x, fmaf(a.y,b.y, a.z*b.z)); }
__device__ __forceinline__ V3 nrm3(V3 a){
    float s = rsqrtf(fmaxf(dot3(a,a), 1e-20f));
    return v3scale(a, s);
}

// ---------- cube face / uv (matches reference _cube_face_uv) ----------
__device__ __forceinline__ void cube_face_uv(V3 d, int& face, float& u, float& v){
    float ax = fabsf(d.x), ay = fabsf(d.y), az = fabsf(d.z);
    bool is_x = (ax >= ay) && (ax >= az);
    bool is_y = (!is_x) && (ay >= az);
    face = is_x ? (d.x >= 0.f ? 0 : 1)
                : (is_y ? (d.y >= 0.f ? 2 : 3)
                        : (d.z >= 0.f ? 4 : 5));
    float ma = fmaxf(is_x ? ax : (is_y ? ay : az), 1e-20f);
    float un = (face == 0) ? -d.z : (face == 1) ? d.z : (face == 5) ? -d.x : d.x;
    float vn = (face == 2) ?  d.z : (face == 3) ? -d.z : -d.y;
    float inv = 1.0f / ma;
    u = un * inv;
    v = vn * inv;
}

// ---------- bilinear cube sample, 3 channels ----------
__device__ __forceinline__ V3 bilinear_cube3(const float* __restrict__ tex, int R,
                                             int face, float u, float v){
    float Rf = (float)R;
    float tu = fmaf(fmaf(u, 0.5f, 0.5f), Rf, -0.5f);
    float tv = fmaf(fmaf(v, 0.5f, 0.5f), Rf, -0.5f);
    float x0 = floorf(tu), y0 = floorf(tv);
    float fx = tu - x0,    fy = tv - y0;
    int x0i = min(max((int)x0,     0), R-1);
    int x1i = min(max((int)x0 + 1, 0), R-1);
    int y0i = min(max((int)y0,     0), R-1);
    int y1i = min(max((int)y0 + 1, 0), R-1);
    const float* base = tex + (size_t)face * R * R * 3;
    const float* r0 = base + (size_t)y0i * R * 3;
    const float* r1 = base + (size_t)y1i * R * 3;
    const float* p00 = r0 + 3*x0i;
    const float* p01 = r0 + 3*x1i;
    const float* p10 = r1 + 3*x0i;
    const float* p11 = r1 + 3*x1i;
    // issue all loads, then blend
    float a0 = p00[0], a1 = p00[1], a2 = p00[2];
    float b0 = p01[0], b1 = p01[1], b2 = p01[2];
    float c0 = p10[0], c1 = p10[1], c2 = p10[2];
    float d0 = p11[0], d1 = p11[1], d2 = p11[2];
    float w00 = (1.f-fx)*(1.f-fy), w01 = fx*(1.f-fy);
    float w10 = (1.f-fx)*fy,       w11 = fx*fy;
    V3 out;
    out.x = a0*w00 + b0*w01 + c0*w10 + d0*w11;
    out.y = a1*w00 + b1*w01 + c1*w10 + d1*w11;
    out.z = a2*w00 + b2*w01 + c2*w10 + d2*w11;
    return out;
}

// ---------- bilinear 2D clamp sample, 2 channels (fg_lut 256x256x2) ----------
__device__ __forceinline__ void sample_fg(const float* __restrict__ lut,
                                          float u, float v, float& fa, float& fb){
    const int W = 256, H = 256;
    float tu = fmaf(u, (float)W, -0.5f);
    float tv = fmaf(v, (float)H, -0.5f);
    float x0 = floorf(tu), y0 = floorf(tv);
    float fx = tu - x0,    fy = tv - y0;
    int x0i = min(max((int)x0,     0), W-1);
    int x1i = min(max((int)x0 + 1, 0), W-1);
    int y0i = min(max((int)y0,     0), H-1);
    int y1i = min(max((int)y0 + 1, 0), H-1);
    const float* r0 = lut + (size_t)y0i * W * 2;
    const float* r1 = lut + (size_t)y1i * W * 2;
    float a0 = r0[2*x0i], a1 = r0[2*x0i+1];
    float b0 = r0[2*x1i], b1 = r0[2*x1i+1];
    float c0 = r1[2*x0i], c1 = r1[2*x0i+1];
    float d0 = r1[2*x1i], d1 = r1[2*x1i+1];
    float w00 = (1.f-fx)*(1.f-fy), w01 = fx*(1.f-fy);
    float w10 = (1.f-fx)*fy,       w11 = fx*fy;
    fa = a0*w00 + b0*w01 + c0*w10 + d0*w11;
    fb = a1*w00 + b1*w01 + c1*w10 + d1*w11;
}

// ---------- linear -> srgb (input already clamped to [0,1]) ----------
__device__ __forceinline__ float lin2srgb(float x){
    // pow(x, 1/2.4) via hw log2/exp2; x > 0.0031308 on that path so log2 is safe
    float xs = (x > 0.0031308f) ? x : 1.0f;
    float p  = __builtin_amdgcn_exp2f(__builtin_amdgcn_logf(xs) * (1.0f/2.4f));
    return (x > 0.0031308f) ? fmaf(1.055f, p, -0.055f) : 12.92f * x;
}

__device__ __forceinline__ float clamp01(float x){ return fminf(fmaxf(x, 0.f), 1.f); }

// ---------- main kernel: one thread per pixel ----------
__global__ __launch_bounds__(256)
void envlight_kernel(const float* __restrict__ gb_pos,
                     const float* __restrict__ gb_normal,
                     const float* __restrict__ basecolor,
                     const float* __restrict__ metallic,
                     const float* __restrict__ roughness,
                     const float* __restrict__ view_pos,
                     const float* __restrict__ diffuse,
                     const float* __restrict__ fg_lut,
                     const float* __restrict__ s0,
                     const float* __restrict__ s1,
                     const float* __restrict__ s2,
                     const float* __restrict__ s3,
                     const float* __restrict__ s4,
                     const float* __restrict__ s5,
                     float* __restrict__ out,
                     int n)
{
    int i = blockIdx.x * blockDim.x + threadIdx.x;
    if (i >= n) return;

    // g-buffer loads (contiguous 12B per lane -> coalesced)
    V3 pos = { gb_pos[3*i],    gb_pos[3*i+1],    gb_pos[3*i+2] };
    V3 nrm = { gb_normal[3*i], gb_normal[3*i+1], gb_normal[3*i+2] };
    V3 bc  = { basecolor[3*i], basecolor[3*i+1], basecolor[3*i+2] };
    float m = metallic[i];
    float r = roughness[i];
    V3 vp  = { view_pos[0], view_pos[1], view_pos[2] };  // uniform -> scalar loads

    V3 wo = nrm3(v3sub(vp, pos));
    float ndv_raw = dot3(wo, nrm);
    V3 refl = nrm3(v3sub(v3scale(nrm, 2.0f*ndv_raw), wo));

    float one_m = 1.0f - m;
    V3 diff_alb = v3scale(bc, one_m);
    V3 spec_alb = { fmaf(m, bc.x, 0.04f*one_m),
                    fmaf(m, bc.y, 0.04f*one_m),
                    fmaf(m, bc.z, 0.04f*one_m) };

    // ambient = diffuse cubemap sampled along normal
    int dface; float du, dv;
    cube_face_uv(nrm, dface, du, dv);
    V3 ambient = bilinear_cube3(diffuse, 16, dface, du, dv);

    // FG LUT: uv = (NdotV, roughness)
    float NdotV = fmaxf(ndv_raw, 0.0001f);
    float fa, fb;
    sample_fg(fg_lut, NdotV, r, fa, fb);

    // mip level (reference _get_mip, then clip to [0,5])
    const float MIN_R = 0.08f, MAX_R = 0.5f;
    float lo = (fminf(fmaxf(r, MIN_R), MAX_R) - MIN_R) / (MAX_R - MIN_R) * 4.0f;
    float hi = (fminf(fmaxf(r, MAX_R), 1.0f) - MAX_R) / (1.0f - MAX_R) + 4.0f;
    float mip = (r < MAX_R) ? lo : hi;
    mip = fminf(fmaxf(mip, 0.0f), 5.0f);

    // Only two adjacent levels have nonzero weight: lerp(floor(mip), floor(mip)+1)
    int l0 = min((int)mip, 5);
    float f = mip - (float)l0;
    int l1 = min(l0 + 1, 5);

    // select mip texture pointers via cndmask chain (uniform ptrs, divergent idx)
    const float* tA = s0;
    tA = (l0 == 1) ? s1 : tA; tA = (l0 == 2) ? s2 : tA;
    tA = (l0 == 3) ? s3 : tA; tA = (l0 == 4) ? s4 : tA; tA = (l0 == 5) ? s5 : tA;
    const float* tB = s0;
    tB = (l1 == 1) ? s1 : tB; tB = (l1 == 2) ? s2 : tB;
    tB = (l1 == 3) ? s3 : tB; tB = (l1 == 4) ? s4 : tB; tB = (l1 == 5) ? s5 : tB;
    int RA = 512 >> l0;
    int RB = 512 >> l1;

    int sface; float su, sv;
    cube_face_uv(refl, sface, su, sv);
    V3 specA = bilinear_cube3(tA, RA, sface, su, sv);
    V3 specB = bilinear_cube3(tB, RB, sface, su, sv);
    V3 spec = { specA.x + (specB.x - specA.x) * f,
                specA.y + (specB.y - specA.y) * f,
                specA.z + (specB.z - specA.z) * f };

    // reflectance = spec_alb * fg.x + fg.y ; rgb = spec*reflectance + ambient*diff_alb
    V3 reflc = { fmaf(spec_alb.x, fa, fb),
                 fmaf(spec_alb.y, fa, fb),
                 fmaf(spec_alb.z, fa, fb) };
    V3 rgb = v3add(v3mul(spec, reflc), v3mul(ambient, diff_alb));

    out[3*i+0] = lin2srgb(clamp01(rgb.x));
    out[3*i+1] = lin2srgb(clamp01(rgb.y));
    out[3*i+2] = lin2srgb(clamp01(rgb.z));
}

extern "C" void kernel_launch(void* const* d_in, const int* in_sizes, int n_in,
                              void* d_out, int out_size, void* d_ws, size_t ws_size,
                              hipStream_t stream) {
    const float* gb_pos    = (const float*)d_in[0];
    const float* gb_normal = (const float*)d_in[1];
    const float* basecolor = (const float*)d_in[2];
    const float* metallic  = (const float*)d_in[3];
    const float* roughness = (const float*)d_in[4];
    const float* view_pos  = (const float*)d_in[5];
    const float* diffuse   = (const float*)d_in[6];
    const float* fg_lut    = (const float*)d_in[7];
    const float* s0        = (const float*)d_in[8];
    const float* s1        = (const float*)d_in[9];
    const float* s2        = (const float*)d_in[10];
    const float* s3        = (const float*)d_in[11];
    const float* s4        = (const float*)d_in[12];
    const float* s5        = (const float*)d_in[13];
    float* out = (float*)d_out;

    int n = in_sizes[0] / 3;   // number of pixels (1024*1024)
    int block = 256;
    int grid = (n + block - 1) / block;
    envlight_kernel<<<grid, block, 0, stream>>>(gb_pos, gb_normal, basecolor,
        metallic, roughness, view_pos, diffuse, fg_lut,
        s0, s1, s2, s3, s4, s5, out, n);
}